// Round 1
// baseline (2037.196 us; speedup 1.0000x reference)
//
#include <hip/hip_runtime.h>

// ---------------- problem constants ----------------
#define NTOK   4096
#define TOPK   4
#define NEXP   32
#define DIM    2048     // D
#define DIHALF 1408     // DI
#define D2I    2816     // 2*DI
#define NKA    (NTOK*TOPK)        // 16384 assignments
#define BMT    128                // M-tile / expert alignment
#define MBUF   (NKA + BMT*NEXP)   // 20480 padded rows (static bound)
#define GRIDM  (MBUF/BMT)         // 160 m-blocks

typedef __attribute__((ext_vector_type(8))) short v8s;   // 8 x bf16 (4 VGPR)
typedef __attribute__((ext_vector_type(4))) float v4f;   // mfma accumulator

// ---------------- bf16 helpers (bit-level, no hip_bf16 types) ----------------
__device__ __forceinline__ float bf2f(unsigned short u){
  unsigned int x = ((unsigned int)u) << 16;
  return __builtin_bit_cast(float, x);
}
__device__ __forceinline__ unsigned short f2bf(float f){
  unsigned int x = __builtin_bit_cast(unsigned int, f);
  x = x + 0x7fffu + ((x >> 16) & 1u);   // round-to-nearest-even
  return (unsigned short)(x >> 16);
}
__device__ __forceinline__ unsigned int packbf(float a, float b){
  return (unsigned int)f2bf(a) | ((unsigned int)f2bf(b) << 16);
}

__device__ __forceinline__ void gload16(const void* g, void* l){
  __builtin_amdgcn_global_load_lds((const __attribute__((address_space(1))) void*)g,
                                   (__attribute__((address_space(3))) void*)l,
                                   16, 0, 0);
}

// ---------------- routing plumbing ----------------
__global__ void k_init(int* __restrict__ counts){
  int t = threadIdx.x;
  if (t < NEXP) counts[t] = 0;
}

__global__ void k_hist(const int* __restrict__ idx, int* __restrict__ counts){
  int a = blockIdx.x*256 + threadIdx.x;
  if (a < NKA) atomicAdd(&counts[idx[a]], 1);
}

// single block; tiny E=32 sequential scan + block->expert map
__global__ void k_scan(const int* __restrict__ counts, int* __restrict__ cursor,
                       int* __restrict__ bexp){
  if (threadIdx.x == 0){
    int as[NEXP], ae[NEXP];
    int acc = 0;
    for (int e=0;e<NEXP;e++){
      as[e] = acc;
      int al = ((counts[e] + BMT - 1) / BMT) * BMT;   // align regions to BM
      ae[e] = acc + al;
      cursor[e] = acc;
      acc += al;
    }
    for (int b=0;b<GRIDM;b++){
      int r = b*BMT, xm = -1;
      for (int e=0;e<NEXP;e++) if (r >= as[e] && r < ae[e]) xm = e;
      bexp[b] = xm;   // -1 => dead zone, gemm blocks exit
    }
  }
}

__global__ void k_rank(const int* __restrict__ idx, int* __restrict__ cursor,
                       int* __restrict__ slot_of){
  int a = blockIdx.x*256 + threadIdx.x;
  if (a < NKA) slot_of[a] = atomicAdd(&cursor[idx[a]], 1);
}

// scatter x rows (fp32) into padded bf16 buffer z
__global__ void k_gather(const float* __restrict__ x, const int* __restrict__ slot_of,
                         unsigned short* __restrict__ z){
  int a = blockIdx.x;               // one block per assignment
  int slot = slot_of[a];
  const float4* src = (const float4*)(x + (size_t)(a / TOPK) * DIM);
  uint2* dst = (uint2*)(z + (size_t)slot * DIM);
  for (int i = threadIdx.x; i < DIM/4; i += 256){
    float4 v = src[i];
    dst[i] = make_uint2(packbf(v.x, v.y), packbf(v.z, v.w));
  }
}

// ---------------- grouped GEMM: C[M x NDIM](bf16) = A[M x KDIM](bf16) * B^T, B=[NDIM x KDIM](fp32) per expert ----------------
// 128x128 tile, BK=64, 4 waves, A via global_load_lds (pre-swizzled source),
// B reg-staged fp32->bf16 with XOR-swizzled ds_write. byte ^= (row&7)<<4 involution.
template<int KDIM, int NDIM>
__global__ __launch_bounds__(256)
void k_gemm(const unsigned short* __restrict__ A,
            const float* __restrict__ Ball,
            unsigned short* __restrict__ C,
            const int* __restrict__ bexp)
{
  __shared__ unsigned short sA[128*64];
  __shared__ unsigned short sB[128*64];

  const int bm = blockIdx.x;
  const int nb = blockIdx.y;
  const int e  = bexp[bm];
  if (e < 0) return;

  const int tid  = threadIdx.x;
  const int lane = tid & 63;
  const int w    = tid >> 6;        // 0..3
  const int wr   = (w >> 1) * 64;   // wave row offset
  const int wc   = (w & 1) * 64;    // wave col offset
  const int r15  = lane & 15;
  const int khi  = lane >> 4;       // 0..3

  const unsigned short* Ab = A + (size_t)bm * 128 * KDIM;
  const float* Bb = Ball + (size_t)e * NDIM * KDIM + (size_t)nb * 128 * KDIM;

  v4f acc[4][4];
  #pragma unroll
  for (int i=0;i<4;i++)
    #pragma unroll
    for (int j=0;j<4;j++) acc[i][j] = 0.0f;

  for (int kt = 0; kt < KDIM/64; ++kt){
    const int k0 = kt*64;

    // ---- stage A (16 KB) via global_load_lds, source pre-permuted for swizzled layout ----
    #pragma unroll
    for (int j=0;j<4;j++){
      int base = (w*4 + j) * 1024;            // wave-uniform LDS byte base
      int p = base + lane*16;                 // this lane's linear dest byte
      int q = p ^ (((p >> 7) & 7) << 4);      // linear pos whose data lands here
      int row = q >> 7;
      int col = (q >> 4) & 7;                 // 8-bf16 chunk within row
      gload16(Ab + (size_t)row*KDIM + k0 + col*8, (char*)sA + base);
    }

    // ---- stage B (128x64 fp32 -> bf16), swizzled ds_write ----
    #pragma unroll
    for (int i=0;i<8;i++){
      int c   = tid + i*256;                  // 0..2047
      int row = c >> 4;
      int k4  = c & 15;
      float4 v = *(const float4*)(Bb + (size_t)row*KDIM + k0 + k4*4);
      unsigned int lo = packbf(v.x, v.y);
      unsigned int hi = packbf(v.z, v.w);
      int b = (row << 7) + (k4 << 3);
      b ^= ((row & 7) << 4);
      *(uint2*)((char*)sB + b) = make_uint2(lo, hi);
    }

    __syncthreads();   // drains vmcnt/lgkmcnt: tile staged + visible

    // ---- compute: 2 x (12 ds_read_b128 + 16 MFMA) ----
    #pragma unroll
    for (int kk=0; kk<2; ++kk){
      const int kby = (kk*32 + khi*8) * 2;   // k byte offset within row
      v8s af[4], bf[4];
      #pragma unroll
      for (int mf=0; mf<4; ++mf){
        int row = wr + mf*16 + r15;
        int b = (row << 7) + kby;
        b ^= ((row & 7) << 4);
        af[mf] = *(const v8s*)((const char*)sA + b);
      }
      #pragma unroll
      for (int nf=0; nf<4; ++nf){
        int row = wc + nf*16 + r15;
        int b = (row << 7) + kby;
        b ^= ((row & 7) << 4);
        bf[nf] = *(const v8s*)((const char*)sB + b);
      }
      #pragma unroll
      for (int mf=0; mf<4; ++mf)
        #pragma unroll
        for (int nf=0; nf<4; ++nf)
          acc[mf][nf] = __builtin_amdgcn_mfma_f32_16x16x32_bf16(af[mf], bf[nf], acc[mf][nf], 0, 0, 0);
    }

    __syncthreads();   // all waves done reading before next stage overwrites
  }

  // ---- epilogue: C/D layout col=lane&15, row=(lane>>4)*4+j ----
  #pragma unroll
  for (int mf=0; mf<4; ++mf){
    #pragma unroll
    for (int nf=0; nf<4; ++nf){
      size_t cbase = (size_t)(bm*128 + wr + mf*16 + khi*4) * NDIM + nb*128 + wc + nf*16 + r15;
      #pragma unroll
      for (int j=0;j<4;j++){
        C[cbase + (size_t)j * NDIM] = f2bf(acc[mf][nf][j]);
      }
    }
  }
}

// ---------------- silu gating: hg = y * silu(gate) ----------------
__global__ void k_gate(const unsigned short* __restrict__ h, unsigned short* __restrict__ hg){
  const int total = MBUF * (DIHALF/8);
  for (int i = blockIdx.x*blockDim.x + threadIdx.x; i < total; i += gridDim.x*blockDim.x){
    int m = i / (DIHALF/8);
    int c = (i - m*(DIHALF/8)) * 8;
    const unsigned short* hr = h + (size_t)m * D2I;
    uint4 yv = *(const uint4*)(hr + c);
    uint4 gv = *(const uint4*)(hr + DIHALF + c);
    unsigned int yy[4] = {yv.x, yv.y, yv.z, yv.w};
    unsigned int gg[4] = {gv.x, gv.y, gv.z, gv.w};
    unsigned int ov[4];
    #pragma unroll
    for (int j=0;j<4;j++){
      float y0 = bf2f((unsigned short)(yy[j] & 0xffffu));
      float y1 = bf2f((unsigned short)(yy[j] >> 16));
      float g0 = bf2f((unsigned short)(gg[j] & 0xffffu));
      float g1 = bf2f((unsigned short)(gg[j] >> 16));
      float s0 = g0 / (1.0f + __expf(-g0));
      float s1 = g1 / (1.0f + __expf(-g1));
      ov[j] = packbf(y0*s0, y1*s1);
    }
    *(uint4*)(hg + (size_t)m * DIHALF + c) = make_uint4(ov[0],ov[1],ov[2],ov[3]);
  }
}

// ---------------- weighted combine over top-k ----------------
__device__ __forceinline__ void acc8(float* o, uint4 v, float w){
  o[0] += w * bf2f((unsigned short)(v.x & 0xffffu));
  o[1] += w * bf2f((unsigned short)(v.x >> 16));
  o[2] += w * bf2f((unsigned short)(v.y & 0xffffu));
  o[3] += w * bf2f((unsigned short)(v.y >> 16));
  o[4] += w * bf2f((unsigned short)(v.z & 0xffffu));
  o[5] += w * bf2f((unsigned short)(v.z >> 16));
  o[6] += w * bf2f((unsigned short)(v.w & 0xffffu));
  o[7] += w * bf2f((unsigned short)(v.w >> 16));
}

__global__ void k_combine(const unsigned short* __restrict__ zo,
                          const float* __restrict__ wts,
                          const int* __restrict__ slot_of,
                          float* __restrict__ out){
  int n = blockIdx.x;
  int c = threadIdx.x * 8;
  float o[8] = {0.f,0.f,0.f,0.f,0.f,0.f,0.f,0.f};
  #pragma unroll
  for (int k=0;k<TOPK;k++){
    float w = wts[n*TOPK + k];
    int s = slot_of[n*TOPK + k];
    uint4 v = *(const uint4*)(zo + (size_t)s*DIM + c);
    acc8(o, v, w);
  }
  float* op = out + (size_t)n*DIM + c;
  *(float4*)(op)     = make_float4(o[0],o[1],o[2],o[3]);
  *(float4*)(op + 4) = make_float4(o[4],o[5],o[6],o[7]);
}

// ---------------- launcher ----------------
extern "C" void kernel_launch(void* const* d_in, const int* in_sizes, int n_in,
                              void* d_out, int out_size, void* d_ws, size_t ws_size,
                              hipStream_t stream){
  (void)in_sizes; (void)n_in; (void)out_size; (void)ws_size;
  const float* x   = (const float*)d_in[0];
  const float* wts = (const float*)d_in[1];
  const float* fc1 = (const float*)d_in[2];   // [E][2816][2048] fp32
  const float* fc2 = (const float*)d_in[3];   // [E][2048][1408] fp32
  const int*   idx = (const int*)d_in[4];
  float* out = (float*)d_out;

  char* ws = (char*)d_ws;
  const size_t ZB  = (size_t)MBUF * DIM    * 2;   // z  (bf16)   ~84 MB
  const size_t HB  = (size_t)MBUF * D2I    * 2;   // h  (bf16)  ~115 MB
  const size_t HGB = (size_t)MBUF * DIHALF * 2;   // hg (bf16)   ~58 MB
  unsigned short* z  = (unsigned short*)ws;
  unsigned short* zo = z;                          // alias: z dead after GEMM1
  unsigned short* h  = (unsigned short*)(ws + ZB);
  unsigned short* hg = (unsigned short*)(ws + ZB + HB);
  int* counts  = (int*)(ws + ZB + HB + HGB);
  int* cursor  = counts + NEXP;
  int* bexp    = cursor + NEXP;
  int* slot_of = bexp + GRIDM;

  k_init   <<<1, 64, 0, stream>>>(counts);
  k_hist   <<<NKA/256, 256, 0, stream>>>(idx, counts);
  k_scan   <<<1, 64, 0, stream>>>(counts, cursor, bexp);
  k_rank   <<<NKA/256, 256, 0, stream>>>(idx, cursor, slot_of);
  k_gather <<<NKA, 256, 0, stream>>>(x, slot_of, z);
  k_gemm<DIM, D2I>   <<<dim3(GRIDM, D2I/128), 256, 0, stream>>>(z,  fc1, h,  bexp);
  k_gate   <<<2048, 256, 0, stream>>>(h, hg);
  k_gemm<DIHALF, DIM><<<dim3(GRIDM, DIM/128), 256, 0, stream>>>(hg, fc2, zo, bexp);
  k_combine<<<NTOK, 256, 0, stream>>>(zo, wts, slot_of, out);
}